// Round 12
// baseline (103.237 us; speedup 1.0000x reference)
//
#include <hip/hip_runtime.h>
#include <math.h>

#define EPSF     1e-12f
#define INV_4PI  0.07957747154594767f
#define LOG2E    1.4426950408889634f

// raw hardware exp2: single v_exp_f32 (|arg| < ~50 here, no subnormal fixup needed)
#define EXP2(x) __builtin_amdgcn_exp2f(x)

// Z = z_approxbis(f), f already clipped to [0, 0.999999]
__device__ __forceinline__ float zapprox(float f) {
    float f2 = f * f;
    float f4 = f2 * f2;
    float f6 = f4 * f2;
    float f8 = f4 * f4;
    float denom = 3.0f - 1.00651f * f2 - 0.962251f * f4 + 1.47353f * f6 - 0.48953f * f8;
    denom = fmaxf(denom, EPSF);
    float p = 1.0f - 2.0f * (1.0f - f) * (1.0f + 1.01524f * f) / denom;
    return 2.0f * f / fmaxf(1.0f - p, 1e-6f);
}

// z / sinh(z), z >= 0
__device__ __forceinline__ float z_over_sinh(float z) {
    float zz = z * z;
    float series = 1.0f - zz / 6.0f + zz * zz / 120.0f;
    float E = __expf(z);
    float s = 0.5f * (E - 1.0f / E);
    float r = z / s;           // NaN at z==0, discarded by select
    return (z < 1e-4f) ? series : r;
}

// per-species: g(dir) = 2^(zx*dx + zy*dy + zz*dz + la)
__device__ __forceinline__ float4 setup_spec(float N, float Fx, float Fy, float Fz) {
    N = fmaxf(N, EPSF);
    float nf = sqrtf(Fx * Fx + Fy * Fy + Fz * Fz);
    float f  = fminf(fmaxf(nf / N, 0.0f), 0.999999f);
    float Z  = zapprox(f);
    float A  = N * INV_4PI * z_over_sinh(Z);
    float sc = Z * LOG2E / fmaxf(nf, EPSF);
    return make_float4(Fx * sc, Fy * sc, Fz * sc, log2f(A));
}

// ---- kernel 1: per-(batch,species) Spec precompute -> d_ws --------------
__global__ __launch_bounds__(256) void spec_kernel(
    const float* __restrict__ F4, float4* __restrict__ ws, int B)
{
    int t = blockIdx.x * blockDim.x + threadIdx.x;
    if (t >= 4 * B) return;
    int b = t >> 2, s = t & 3;
    const float4* row = (const float4*)(F4 + (size_t)b * 24);
    float N, Fx, Fy, Fz;
    if (s == 0) {                       // e
        float4 a = row[0];  N = a.w; Fx = a.x; Fy = a.y; Fz = a.z;
    } else if (s == 1) {                // ebar
        float4 a = row[3];  N = a.w; Fx = a.x; Fy = a.y; Fz = a.z;
    } else if (s == 2) {                // x = mean(flavors 1,2) of nu
        float4 a = row[1], c = row[2];
        N = 0.5f * (a.w + c.w); Fx = 0.5f * (a.x + c.x);
        Fy = 0.5f * (a.y + c.y); Fz = 0.5f * (a.z + c.z);
    } else {                            // xbar
        float4 a = row[4], c = row[5];
        N = 0.5f * (a.w + c.w); Fx = 0.5f * (a.x + c.x);
        Fy = 0.5f * (a.y + c.y); Fz = 0.5f * (a.z + c.z);
    }
    ws[(size_t)b * 4 + s] = setup_spec(N, Fx, Fy, Fz);
}

// ---- kernel 2: hot quadrature loop --------------------------------------
// SCALAR accumulation with a deliberately minimal live set (~56 regs:
// 16 consts + 24 accums + q4 + g4 + transients). __launch_bounds__(256,8)
// caps the unified VGPR+AGPR budget at 64/wave: everything fits in arch
// VGPRs, NO AGPR banking is possible, and 8 waves/SIMD are resident.
// This trades ~1.45x issue cycles (scalar vs packed) for 3.3x latency
// hiding + removal of the AGPR read/write tax that capped R6-R11 at ~40us.
__global__ __launch_bounds__(256, 8) void box3d_kernel(
    const float4* __restrict__ ws,
    const float* __restrict__ dxp, const float* __restrict__ dyp,
    const float* __restrict__ dzp, const float* __restrict__ qwp,
    float* __restrict__ out, int B, int ndir)
{
    __shared__ float4 sdir[800];   // (dx, dy, dz, w) per direction, 12.8 KB
    for (int d = threadIdx.x; d < ndir; d += blockDim.x)
        sdir[d] = make_float4(dxp[d], dyp[d], dzp[d], qwp[d]);
    __syncthreads();

    const int sub = threadIdx.x & 15;        // lane within 16-group
    const int b = blockIdx.x * 16 + (threadIdx.x >> 4);
    if (b >= B) return;

    // specs precomputed by spec_kernel: (zx, zy, zz, la) per species
    const float4* wsb = ws + (size_t)b * 4;
    const float4 f0 = wsb[0], f1 = wsb[1], f2 = wsb[2], f3 = wsb[3];

    // 24 scalar accumulators; ip/im derived afterwards from masked sums
    float ut0 = 0, ut1 = 0, ut2 = 0, ut3 = 0;   // sum w*m*u        (u = g_e - g_x)
    float up0 = 0, up1 = 0, up2 = 0, up3 = 0;   // sum_{delta>=0} w*m*u
    float vt0 = 0, vt1 = 0, vt2 = 0, vt3 = 0;   // sum w*m*v        (v = g_ebar - g_xbar)
    float vp0 = 0, vp1 = 0, vp2 = 0, vp3 = 0;   // sum_{delta>=0} w*m*v
    float gx0 = 0, gx1 = 0, gx2 = 0, gx3 = 0;   // sum w*m*g_x
    float gy0 = 0, gy1 = 0, gy2 = 0, gy3 = 0;   // sum w*m*g_xbar

    for (int d = sub; d < ndir; d += 16) {
        float4 q = sdir[d];
        float g0 = EXP2(fmaf(f0.x, q.x, fmaf(f0.y, q.y, fmaf(f0.z, q.z, f0.w))));
        float g1 = EXP2(fmaf(f1.x, q.x, fmaf(f1.y, q.y, fmaf(f1.z, q.z, f1.w))));
        float g2 = EXP2(fmaf(f2.x, q.x, fmaf(f2.y, q.y, fmaf(f2.z, q.z, f2.w))));
        float g3 = EXP2(fmaf(f3.x, q.x, fmaf(f3.y, q.y, fmaf(f3.z, q.z, f3.w))));

        float u = g0 - g2, v = g1 - g3;      // delta = u - v; w > 0
        bool pos = (u >= v);
        float wu = q.w * u,  wv = q.w * v;
        float wup = pos ? wu : 0.0f;
        float wvp = pos ? wv : 0.0f;
        float w2 = q.w * g2, w3 = q.w * g3;

        ut0 += wu;  up0 += wup;  vt0 += wv;  vp0 += wvp;  gx0 += w2;  gy0 += w3;
        ut1 = fmaf(wu, q.x, ut1);  up1 = fmaf(wup, q.x, up1);
        vt1 = fmaf(wv, q.x, vt1);  vp1 = fmaf(wvp, q.x, vp1);
        gx1 = fmaf(w2, q.x, gx1);  gy1 = fmaf(w3, q.x, gy1);
        ut2 = fmaf(wu, q.y, ut2);  up2 = fmaf(wup, q.y, up2);
        vt2 = fmaf(wv, q.y, vt2);  vp2 = fmaf(wvp, q.y, vp2);
        gx2 = fmaf(w2, q.y, gx2);  gy2 = fmaf(w3, q.y, gy2);
        ut3 = fmaf(wu, q.z, ut3);  up3 = fmaf(wup, q.z, up3);
        vt3 = fmaf(wv, q.z, vt3);  vp3 = fmaf(wvp, q.z, vp3);
        gx3 = fmaf(w2, q.z, gx3);  gy3 = fmaf(w3, q.z, gy3);
    }

    // ---- butterfly reduction within the 16-lane group (masks 1,2,4,8) ----
    #pragma unroll
    for (int msk = 1; msk <= 8; msk <<= 1) {
        ut0 += __shfl_xor(ut0, msk);  ut1 += __shfl_xor(ut1, msk);
        ut2 += __shfl_xor(ut2, msk);  ut3 += __shfl_xor(ut3, msk);
        up0 += __shfl_xor(up0, msk);  up1 += __shfl_xor(up1, msk);
        up2 += __shfl_xor(up2, msk);  up3 += __shfl_xor(up3, msk);
        vt0 += __shfl_xor(vt0, msk);  vt1 += __shfl_xor(vt1, msk);
        vt2 += __shfl_xor(vt2, msk);  vt3 += __shfl_xor(vt3, msk);
        vp0 += __shfl_xor(vp0, msk);  vp1 += __shfl_xor(vp1, msk);
        vp2 += __shfl_xor(vp2, msk);  vp3 += __shfl_xor(vp3, msk);
        gx0 += __shfl_xor(gx0, msk);  gx1 += __shfl_xor(gx1, msk);
        gx2 += __shfl_xor(gx2, msk);  gx3 += __shfl_xor(gx3, msk);
        gy0 += __shfl_xor(gy0, msk);  gy1 += __shfl_xor(gy1, msk);
        gy2 += __shfl_xor(gy2, msk);  gy3 += __shfl_xor(gy3, msk);
    }

    // Iplus = sum_{delta>=0} w*delta = up0 - vp0 (identical masked sums)
    // Iminus = Iplus - sum w*delta
    float ip = fmaxf(up0 - vp0, 0.0f);
    float im = fmaxf(ip - ut0 + vt0, 0.0f);

    float Ips = fmaxf(ip, EPSF), Ims = fmaxf(im, EPSF);
    const float third = 1.0f / 3.0f;
    float cp, cn;
    if (ip < im) {
        cp = third;
        cn = fminf(fmaxf(1.0f - (2.0f / 3.0f) * (Ips / Ims), 0.0f), 1.0f);
    } else {
        cp = fminf(fmaxf(1.0f - (2.0f / 3.0f) * (Ims / Ips), 0.0f), 1.0f);
        cn = third;
    }

    // ---- final moments: P = cp*up + cn*(ut-up); out per reference layout ----
    float P0 = cp * up0 + cn * (ut0 - up0), Q0 = cp * vp0 + cn * (vt0 - vp0);
    float P1 = cp * up1 + cn * (ut1 - up1), Q1 = cp * vp1 + cn * (vt1 - vp1);
    float P2 = cp * up2 + cn * (ut2 - up2), Q2 = cp * vp2 + cn * (vt2 - vp2);
    float P3 = cp * up3 + cn * (ut3 - up3), Q3 = cp * vp3 + cn * (vt3 - vp3);

    // memory layout per batch (6 float4): [e, x, x, ebar, xbar, xbar], each (Fx,Fy,Fz,N)
    float4* o4 = (float4*)out + (size_t)b * 6;
    if (sub == 0) {
        o4[0] = make_float4(gx1 + P1, gx2 + P2, gx3 + P3, gx0 + P0);                       // e
    } else if (sub == 1) {
        o4[1] = make_float4(gx1 + 0.5f * (ut1 - P1), gx2 + 0.5f * (ut2 - P2),
                            gx3 + 0.5f * (ut3 - P3), gx0 + 0.5f * (ut0 - P0));             // x
    } else if (sub == 2) {
        o4[2] = make_float4(gx1 + 0.5f * (ut1 - P1), gx2 + 0.5f * (ut2 - P2),
                            gx3 + 0.5f * (ut3 - P3), gx0 + 0.5f * (ut0 - P0));             // x
    } else if (sub == 3) {
        o4[3] = make_float4(gy1 + Q1, gy2 + Q2, gy3 + Q3, gy0 + Q0);                       // ebar
    } else if (sub == 4) {
        o4[4] = make_float4(gy1 + 0.5f * (vt1 - Q1), gy2 + 0.5f * (vt2 - Q2),
                            gy3 + 0.5f * (vt3 - Q3), gy0 + 0.5f * (vt0 - Q0));             // xbar
    } else if (sub == 5) {
        o4[5] = make_float4(gy1 + 0.5f * (vt1 - Q1), gy2 + 0.5f * (vt2 - Q2),
                            gy3 + 0.5f * (vt3 - Q3), gy0 + 0.5f * (vt0 - Q0));             // xbar
    } else if (sub == 6) {
        out[(size_t)B * 24 + b] = sqrtf(fmaxf(ip * im, 0.0f));                             // growth
    }
}

extern "C" void kernel_launch(void* const* d_in, const int* in_sizes, int n_in,
                              void* d_out, int out_size, void* d_ws, size_t ws_size,
                              hipStream_t stream) {
    const float* F4 = (const float*)d_in[0];
    const float* dx = (const float*)d_in[1];
    const float* dy = (const float*)d_in[2];
    const float* dz = (const float*)d_in[3];
    const float* qw = (const float*)d_in[4];
    float* out = (float*)d_out;

    int B = in_sizes[0] / 24;     // (B, 2, 3, 4)
    int ndir = in_sizes[1];       // 800
    float4* ws = (float4*)d_ws;   // B*4 float4 specs (2 MB at B=32768)

    int t1 = 4 * B;
    spec_kernel<<<(t1 + 255) / 256, 256, 0, stream>>>(F4, ws, B);
    int blocks = (B + 15) / 16;   // 16 batch elements per 256-thread block
    box3d_kernel<<<blocks, 256, 0, stream>>>(ws, dx, dy, dz, qw, out, B, ndir);
}

// Round 13
// 96.163 us; speedup vs baseline: 1.0736x; 1.0736x over previous
//
#include <hip/hip_runtime.h>
#include <math.h>

#define EPSF     1e-12f
#define INV_4PI  0.07957747154594767f
#define LOG2E    1.4426950408889634f

typedef float v2f __attribute__((ext_vector_type(2)));

#if __has_builtin(__builtin_elementwise_fma)
#define FMA2(a, b, c) __builtin_elementwise_fma((a), (b), (c))
#else
#define FMA2(a, b, c) ((a) * (b) + (c))
#endif

// raw hardware exp2: single v_exp_f32 (|arg| < ~50 here, no subnormal fixup needed)
// measured: v_exp_f32 ~16 cyc/wave-inst (4-lane trans unit) — R11/R12 busy-cycle fit
#define EXP2(x) __builtin_amdgcn_exp2f(x)

// Z = z_approxbis(f), f already clipped to [0, 0.999999]
__device__ __forceinline__ float zapprox(float f) {
    float f2 = f * f;
    float f4 = f2 * f2;
    float f6 = f4 * f2;
    float f8 = f4 * f4;
    float denom = 3.0f - 1.00651f * f2 - 0.962251f * f4 + 1.47353f * f6 - 0.48953f * f8;
    denom = fmaxf(denom, EPSF);
    float p = 1.0f - 2.0f * (1.0f - f) * (1.0f + 1.01524f * f) / denom;
    return 2.0f * f / fmaxf(1.0f - p, 1e-6f);
}

// z / sinh(z), z >= 0
__device__ __forceinline__ float z_over_sinh(float z) {
    float zz = z * z;
    float series = 1.0f - zz / 6.0f + zz * zz / 120.0f;
    float E = __expf(z);
    float s = 0.5f * (E - 1.0f / E);
    float r = z / s;           // NaN at z==0, discarded by select
    return (z < 1e-4f) ? series : r;
}

// per-species: g(dir) = 2^(zx*dx + zy*dy + zz*dz + la)
__device__ __forceinline__ float4 setup_spec(float N, float Fx, float Fy, float Fz) {
    N = fmaxf(N, EPSF);
    float nf = sqrtf(Fx * Fx + Fy * Fy + Fz * Fz);
    float f  = fminf(fmaxf(nf / N, 0.0f), 0.999999f);
    float Z  = zapprox(f);
    float A  = N * INV_4PI * z_over_sinh(Z);
    float sc = Z * LOG2E / fmaxf(nf, EPSF);
    return make_float4(Fx * sc, Fy * sc, Fz * sc, log2f(A));
}

// ---- kernel 1: per-(batch,species) Spec precompute -> d_ws --------------
__global__ __launch_bounds__(256) void spec_kernel(
    const float* __restrict__ F4, float4* __restrict__ ws, int B)
{
    int t = blockIdx.x * blockDim.x + threadIdx.x;
    if (t >= 4 * B) return;
    int b = t >> 2, s = t & 3;
    const float4* row = (const float4*)(F4 + (size_t)b * 24);
    float N, Fx, Fy, Fz;
    if (s == 0) {                       // e
        float4 a = row[0];  N = a.w; Fx = a.x; Fy = a.y; Fz = a.z;
    } else if (s == 1) {                // ebar
        float4 a = row[3];  N = a.w; Fx = a.x; Fy = a.y; Fz = a.z;
    } else if (s == 2) {                // x = mean(flavors 1,2) of nu
        float4 a = row[1], c = row[2];
        N = 0.5f * (a.w + c.w); Fx = 0.5f * (a.x + c.x);
        Fy = 0.5f * (a.y + c.y); Fz = 0.5f * (a.z + c.z);
    } else {                            // xbar
        float4 a = row[4], c = row[5];
        N = 0.5f * (a.w + c.w); Fx = 0.5f * (a.x + c.x);
        Fy = 0.5f * (a.y + c.y); Fz = 0.5f * (a.z + c.z);
    }
    ws[(size_t)b * 4 + s] = setup_spec(N, Fx, Fy, Fz);
}

__device__ __forceinline__ v2f bcast(float x) { v2f r; r.x = x; r.y = x; return r; }

// ---- kernel 2: hot quadrature loop --------------------------------------
// Packed (2 dirs/iter) — measured lowest issue volume (R11: busy 54-60k
// cyc/SIMD vs scalar R12 89k). Key change: unroll(disable). The compiler's
// auto-unroll x2 duplicated ~35 temp registers, pushing the live set from
// ~130 to ~170 and capping residency at ~3 waves/SIMD (the 37k stall cycles
// in R11). No manual prefetch (R11 showed it worth only ~5%, costs 8 regs).
__global__ __launch_bounds__(256, 4) void box3d_kernel(
    const float4* __restrict__ ws,
    const float* __restrict__ dxp, const float* __restrict__ dyp,
    const float* __restrict__ dzp, const float* __restrict__ qwp,
    float* __restrict__ out, int B, int ndir)
{
    // pair-interleaved LDS: per direction-pair p,
    //   sAB[p] = (qx0,qx1, qy0,qy1)   sCD[p] = (qz0,qz1, qw0,qw1)
    __shared__ float4 sAB[400], sCD[400];
    const int npair = ndir >> 1;             // 400
    for (int p = threadIdx.x; p < npair; p += blockDim.x) {
        int d0 = 2 * p;
        sAB[p] = make_float4(dxp[d0], dxp[d0 + 1], dyp[d0], dyp[d0 + 1]);
        sCD[p] = make_float4(dzp[d0], dzp[d0 + 1], qwp[d0], qwp[d0 + 1]);
    }
    __syncthreads();

    const int sub = threadIdx.x & 15;        // lane within 16-group
    const int b = blockIdx.x * 16 + (threadIdx.x >> 4);
    if (b >= B) return;

    // specs precomputed by spec_kernel
    const float4* wsb = ws + (size_t)b * 4;
    float4 f0 = wsb[0], f1 = wsb[1], f2 = wsb[2], f3 = wsb[3];
    v2f zx0 = bcast(f0.x), zy0 = bcast(f0.y), zz0 = bcast(f0.z), la0 = bcast(f0.w);
    v2f zx1 = bcast(f1.x), zy1 = bcast(f1.y), zz1 = bcast(f1.z), la1 = bcast(f1.w);
    v2f zx2 = bcast(f2.x), zy2 = bcast(f2.y), zz2 = bcast(f2.z), la2 = bcast(f2.w);
    v2f zx3 = bcast(f3.x), zy3 = bcast(f3.y), zz3 = bcast(f3.z), la3 = bcast(f3.w);

    // masked moment sums; ip/im derived afterwards from up0/vp0/ut0/vt0
    const v2f zero = bcast(0.0f);
    v2f aut0 = zero, aut1 = zero, aut2 = zero, aut3 = zero;
    v2f aup0 = zero, aup1 = zero, aup2 = zero, aup3 = zero;
    v2f avt0 = zero, avt1 = zero, avt2 = zero, avt3 = zero;
    v2f avp0 = zero, avp1 = zero, avp2 = zero, avp3 = zero;
    v2f agx0 = zero, agx1 = zero, agx2 = zero, agx3 = zero;
    v2f agy0 = zero, agy1 = zero, agy2 = zero, agy3 = zero;

    #pragma clang loop unroll(disable)
    for (int p = sub; p < npair; p += 16) {
        float4 ab = sAB[p];
        float4 cd = sCD[p];
        v2f qx; qx.x = ab.x; qx.y = ab.y;
        v2f qy; qy.x = ab.z; qy.y = ab.w;
        v2f qz; qz.x = cd.x; qz.y = cd.y;
        v2f qw; qw.x = cd.z; qw.y = cd.w;

        v2f t0 = FMA2(zx0, qx, FMA2(zy0, qy, FMA2(zz0, qz, la0)));
        v2f t1 = FMA2(zx1, qx, FMA2(zy1, qy, FMA2(zz1, qz, la1)));
        v2f t2 = FMA2(zx2, qx, FMA2(zy2, qy, FMA2(zz2, qz, la2)));
        v2f t3 = FMA2(zx3, qx, FMA2(zy3, qy, FMA2(zz3, qz, la3)));
        v2f g0, g1, g2, g3;
        g0.x = EXP2(t0.x); g0.y = EXP2(t0.y);
        g1.x = EXP2(t1.x); g1.y = EXP2(t1.y);
        g2.x = EXP2(t2.x); g2.y = EXP2(t2.y);
        g3.x = EXP2(t3.x); g3.y = EXP2(t3.y);

        v2f u = g0 - g2, v = g1 - g3;        // delta = u - v; w > 0
        v2f wu = qw * u, wv = qw * v;
        v2f wup, wvp;                        // masked (delta >= 0) terms
        wup.x = (u.x >= v.x) ? wu.x : 0.0f;
        wup.y = (u.y >= v.y) ? wu.y : 0.0f;
        wvp.x = (u.x >= v.x) ? wv.x : 0.0f;
        wvp.y = (u.y >= v.y) ? wv.y : 0.0f;
        v2f w2 = qw * g2, w3 = qw * g3;

        aut0 += wu;  aup0 += wup;  avt0 += wv;  avp0 += wvp;  agx0 += w2;  agy0 += w3;
        aut1 = FMA2(wu, qx, aut1);  aup1 = FMA2(wup, qx, aup1);
        avt1 = FMA2(wv, qx, avt1);  avp1 = FMA2(wvp, qx, avp1);
        agx1 = FMA2(w2, qx, agx1);  agy1 = FMA2(w3, qx, agy1);
        aut2 = FMA2(wu, qy, aut2);  aup2 = FMA2(wup, qy, aup2);
        avt2 = FMA2(wv, qy, avt2);  avp2 = FMA2(wvp, qy, avp2);
        agx2 = FMA2(w2, qy, agx2);  agy2 = FMA2(w3, qy, agy2);
        aut3 = FMA2(wu, qz, aut3);  aup3 = FMA2(wup, qz, aup3);
        avt3 = FMA2(wv, qz, avt3);  avp3 = FMA2(wvp, qz, avp3);
        agx3 = FMA2(w2, qz, agx3);  agy3 = FMA2(w3, qz, agy3);
    }

    // ---- collapse packed pairs, then butterfly over the 16-lane group ----
    float ut0 = aut0.x + aut0.y, ut1 = aut1.x + aut1.y, ut2 = aut2.x + aut2.y, ut3 = aut3.x + aut3.y;
    float up0 = aup0.x + aup0.y, up1 = aup1.x + aup1.y, up2 = aup2.x + aup2.y, up3 = aup3.x + aup3.y;
    float vt0 = avt0.x + avt0.y, vt1 = avt1.x + avt1.y, vt2 = avt2.x + avt2.y, vt3 = avt3.x + avt3.y;
    float vp0 = avp0.x + avp0.y, vp1 = avp1.x + avp1.y, vp2 = avp2.x + avp2.y, vp3 = avp3.x + avp3.y;
    float gx0 = agx0.x + agx0.y, gx1 = agx1.x + agx1.y, gx2 = agx2.x + agx2.y, gx3 = agx3.x + agx3.y;
    float gy0 = agy0.x + agy0.y, gy1 = agy1.x + agy1.y, gy2 = agy2.x + agy2.y, gy3 = agy3.x + agy3.y;

    #pragma unroll
    for (int msk = 1; msk <= 8; msk <<= 1) {
        ut0 += __shfl_xor(ut0, msk);  ut1 += __shfl_xor(ut1, msk);
        ut2 += __shfl_xor(ut2, msk);  ut3 += __shfl_xor(ut3, msk);
        up0 += __shfl_xor(up0, msk);  up1 += __shfl_xor(up1, msk);
        up2 += __shfl_xor(up2, msk);  up3 += __shfl_xor(up3, msk);
        vt0 += __shfl_xor(vt0, msk);  vt1 += __shfl_xor(vt1, msk);
        vt2 += __shfl_xor(vt2, msk);  vt3 += __shfl_xor(vt3, msk);
        vp0 += __shfl_xor(vp0, msk);  vp1 += __shfl_xor(vp1, msk);
        vp2 += __shfl_xor(vp2, msk);  vp3 += __shfl_xor(vp3, msk);
        gx0 += __shfl_xor(gx0, msk);  gx1 += __shfl_xor(gx1, msk);
        gx2 += __shfl_xor(gx2, msk);  gx3 += __shfl_xor(gx3, msk);
        gy0 += __shfl_xor(gy0, msk);  gy1 += __shfl_xor(gy1, msk);
        gy2 += __shfl_xor(gy2, msk);  gy3 += __shfl_xor(gy3, msk);
    }

    // Iplus = sum_{delta>=0} w*delta = up0 - vp0 (identical masked sums)
    // Iminus = Iplus - sum w*delta
    float ip = fmaxf(up0 - vp0, 0.0f);
    float im = fmaxf(ip - ut0 + vt0, 0.0f);

    float Ips = fmaxf(ip, EPSF), Ims = fmaxf(im, EPSF);
    const float third = 1.0f / 3.0f;
    float cp, cn;
    if (ip < im) {
        cp = third;
        cn = fminf(fmaxf(1.0f - (2.0f / 3.0f) * (Ips / Ims), 0.0f), 1.0f);
    } else {
        cp = fminf(fmaxf(1.0f - (2.0f / 3.0f) * (Ims / Ips), 0.0f), 1.0f);
        cn = third;
    }

    // ---- final moments: P = cp*up + cn*(ut-up); out per reference layout ----
    float P0 = cp * up0 + cn * (ut0 - up0), Q0 = cp * vp0 + cn * (vt0 - vp0);
    float P1 = cp * up1 + cn * (ut1 - up1), Q1 = cp * vp1 + cn * (vt1 - vp1);
    float P2 = cp * up2 + cn * (ut2 - up2), Q2 = cp * vp2 + cn * (vt2 - vp2);
    float P3 = cp * up3 + cn * (ut3 - up3), Q3 = cp * vp3 + cn * (vt3 - vp3);

    // memory layout per batch (6 float4): [e, x, x, ebar, xbar, xbar], each (Fx,Fy,Fz,N)
    float4* o4 = (float4*)out + (size_t)b * 6;
    if (sub == 0) {
        o4[0] = make_float4(gx1 + P1, gx2 + P2, gx3 + P3, gx0 + P0);                       // e
    } else if (sub == 1) {
        o4[1] = make_float4(gx1 + 0.5f * (ut1 - P1), gx2 + 0.5f * (ut2 - P2),
                            gx3 + 0.5f * (ut3 - P3), gx0 + 0.5f * (ut0 - P0));             // x
    } else if (sub == 2) {
        o4[2] = make_float4(gx1 + 0.5f * (ut1 - P1), gx2 + 0.5f * (ut2 - P2),
                            gx3 + 0.5f * (ut3 - P3), gx0 + 0.5f * (ut0 - P0));             // x
    } else if (sub == 3) {
        o4[3] = make_float4(gy1 + Q1, gy2 + Q2, gy3 + Q3, gy0 + Q0);                       // ebar
    } else if (sub == 4) {
        o4[4] = make_float4(gy1 + 0.5f * (vt1 - Q1), gy2 + 0.5f * (vt2 - Q2),
                            gy3 + 0.5f * (vt3 - Q3), gy0 + 0.5f * (vt0 - Q0));             // xbar
    } else if (sub == 5) {
        o4[5] = make_float4(gy1 + 0.5f * (vt1 - Q1), gy2 + 0.5f * (vt2 - Q2),
                            gy3 + 0.5f * (vt3 - Q3), gy0 + 0.5f * (vt0 - Q0));             // xbar
    } else if (sub == 6) {
        out[(size_t)B * 24 + b] = sqrtf(fmaxf(ip * im, 0.0f));                             // growth
    }
}

extern "C" void kernel_launch(void* const* d_in, const int* in_sizes, int n_in,
                              void* d_out, int out_size, void* d_ws, size_t ws_size,
                              hipStream_t stream) {
    const float* F4 = (const float*)d_in[0];
    const float* dx = (const float*)d_in[1];
    const float* dy = (const float*)d_in[2];
    const float* dz = (const float*)d_in[3];
    const float* qw = (const float*)d_in[4];
    float* out = (float*)d_out;

    int B = in_sizes[0] / 24;     // (B, 2, 3, 4)
    int ndir = in_sizes[1];       // 800
    float4* ws = (float4*)d_ws;   // B*4 float4 specs (2 MB at B=32768)

    int t1 = 4 * B;
    spec_kernel<<<(t1 + 255) / 256, 256, 0, stream>>>(F4, ws, B);
    int blocks = (B + 15) / 16;   // 16 batch elements per 256-thread block
    box3d_kernel<<<blocks, 256, 0, stream>>>(ws, dx, dy, dz, qw, out, B, ndir);
}